// Round 1
// baseline (101.117 us; speedup 1.0000x reference)
//
#include <hip/hip_runtime.h>

#define BATCH 4
#define SEQ   2048
#define EMB   128
#define NH    16
#define DK    8

// log2(e) / sqrt(8): fold softmax temperature into exp2 (pre-multiplied into qf)
#define QSCALE 0.510069726f

typedef _Float16 v4h  __attribute__((ext_vector_type(4)));
typedef _Float16 v8h  __attribute__((ext_vector_type(8)));
typedef __fp16   v2fp __attribute__((ext_vector_type(2)));
typedef float    v4f  __attribute__((ext_vector_type(4)));
typedef float    v16f __attribute__((ext_vector_type(16)));

#define CHUNK  512
#define VTP    520             // VT col pitch (f16): 260 dwords %32 = 4 -> 2-way max

// ---------------------------------------------------------------------------
// R16: key-split for occupancy. Same math as R15 (32x32 MFMA attention,
// HW-verified layouts), but each block now handles HALF the keys (2 chunks
// of 512) for its 128 q rows and writes an UNNORMALIZED f32 partial
// (8 dims + denominator) to workspace. Plain-exp softmax => partials
// combine by simple addition (no max rescaling); proj combines while
// staging Ah. Total exp/MFMA/staging work unchanged; grid 1024 -> 2048
// blocks = 8 blocks/CU (LDS 18.9 KB x 8 = 151.5 KB) = 32 waves/CU,
// doubling the wave pool that hides the kf->mfma->exp->pack->mfma chain.
// qf computed directly from x (8 cos per half-lane) since the q-containing
// chunk may live in the other block's key half.
//
// Layouts (HW-verified): S^T = mfma_32x32x16(A=K, B=Q^T); C/D layout
// col=L&31, row=(reg&3)+8(reg>>2)+4(L>>5). P=exp2(S^T) packs with pkrtz in
// natural reg order into the PV B-frag PROVIDED V^T is stored with key-index
// bits 2<->3 swapped. qf=0 on half1 kills the k=8..15 padding. Ones-row d=8
// of V^T gives the partial denominator; rows 9..31 garbage, never stored.
// ---------------------------------------------------------------------------
__launch_bounds__(256, 8)
__global__ void attn_kernel(const float* __restrict__ x,
                            const float* __restrict__ theta,
                            float* __restrict__ PO   /* [2][B][NH][S][8] f32 */,
                            float* __restrict__ DEN  /* [2][B][NH][S] f32 */) {
  __shared__ __align__(16) _Float16 Kl[CHUNK * 8];   // 8 KB: [key][8 dims]
  __shared__ __align__(16) _Float16 VT[10][VTP];     // 10.2 KB: d 0-7, 8=ones, 9=junk

  const int tid = threadIdx.x;
  const int L   = tid & 63;
  const int ln  = L & 31;
  const int hf  = L >> 5;           // lane half
  const int wv  = tid >> 6;         // wave 0..3
  const int bx  = blockIdx.x;
  const int bh     = bx >> 5;       // 64 (b,h) pairs
  const int qchunk = (bx >> 1) & 15;
  const int kh     = bx & 1;        // key half: chunks {0,1} or {2,3}
  const int qb     = qchunk * 128 + wv * 32;   // wave's 32 q rows
  const int b = bh >> 4;
  const int h = bh & 15;

  float th[DK];
#pragma unroll
  for (int i = 0; i < DK; ++i) th[i] = theta[i];

  // VT row 8 = ones (denominator; persists across restages), row 9 = 0
  for (int i = tid; i < VTP; i += 256) {
    VT[8][i] = (_Float16)1.0f;
    VT[9][i] = (_Float16)0.0f;
  }

  const int mrow = (ln < 9) ? ln : 9;   // clamped VT row for PV A-frag
  const float* xb = x + (size_t)b * SEQ * EMB + h * DK;

  float4 pa0, pa1, pb0, pb1;        // prefetched x rows (keys tid, tid+256)
  {
    const float* xp = xb + (size_t)(kh * 2 * CHUNK + tid) * EMB;
    pa0 = *(const float4*)(xp);
    pa1 = *(const float4*)(xp + 4);
    pb0 = *(const float4*)(xp + 256 * EMB);
    pb1 = *(const float4*)(xp + 256 * EMB + 4);
  }

  // qf directly from x for this wave's 32 q rows (half0 lanes only; half1
  // stays 0 to kill the k=8..15 MFMA padding)
  v8h qf = {0, 0, 0, 0, 0, 0, 0, 0};
  if (hf == 0) {
    const float* xq = xb + (size_t)(qb + ln) * EMB;
    const float4 q0 = *(const float4*)(xq);
    const float4 q1 = *(const float4*)(xq + 4);
    float r[8];
    r[0] = __cosf(q0.x + th[0]);
    r[1] = r[0] * __cosf(q0.y + th[1]);
    r[2] = r[1] * __cosf(q0.z + th[2]);
    r[3] = r[2] * __cosf(q0.w + th[3]);
    r[4] = r[3] * __cosf(q1.x + th[4]);
    r[5] = r[4] * __cosf(q1.y + th[5]);
    r[6] = r[5] * __cosf(q1.z + th[6]);
    r[7] = r[6] * __cosf(q1.w + th[7]);
    _Float16 hq[8];
#pragma unroll
    for (int i = 0; i < 8; ++i) hq[i] = (_Float16)r[i];
    const _Float16 qs = (_Float16)QSCALE;
    const v8h qsc = {qs, qs, qs, qs, qs, qs, qs, qs};
    const v8h qv  = {hq[0], hq[1], hq[2], hq[3], hq[4], hq[5], hq[6], hq[7]};
    qf = qv * qsc;
  }

  v16f acc;
#pragma unroll
  for (int i = 0; i < 16; ++i) acc[i] = 0.f;
  v16f zf;
#pragma unroll
  for (int i = 0; i < 16; ++i) zf[i] = 0.f;

  for (int cc = 0; cc < 2; ++cc) {
    if (cc) __syncthreads();

    // ---- stage: features for keys tid, tid+256 (16 B/lane Kl writes) ----
    {
      float r0[8], r1[8];
      r0[0] = __cosf(pa0.x + th[0]);
      r0[1] = r0[0] * __cosf(pa0.y + th[1]);
      r0[2] = r0[1] * __cosf(pa0.z + th[2]);
      r0[3] = r0[2] * __cosf(pa0.w + th[3]);
      r0[4] = r0[3] * __cosf(pa1.x + th[4]);
      r0[5] = r0[4] * __cosf(pa1.y + th[5]);
      r0[6] = r0[5] * __cosf(pa1.z + th[6]);
      r0[7] = r0[6] * __cosf(pa1.w + th[7]);
      r1[0] = __cosf(pb0.x + th[0]);
      r1[1] = r1[0] * __cosf(pb0.y + th[1]);
      r1[2] = r1[1] * __cosf(pb0.z + th[2]);
      r1[3] = r1[2] * __cosf(pb0.w + th[3]);
      r1[4] = r1[3] * __cosf(pb1.x + th[4]);
      r1[5] = r1[4] * __cosf(pb1.y + th[5]);
      r1[6] = r1[5] * __cosf(pb1.z + th[6]);
      r1[7] = r1[6] * __cosf(pb1.w + th[7]);

      _Float16 h0[8], h1[8];
#pragma unroll
      for (int i = 0; i < 8; ++i) { h0[i] = (_Float16)r0[i]; h1[i] = (_Float16)r1[i]; }

      union { v4h v[2]; float4 f; } u0, u1;
      u0.v[0] = (v4h){h0[0], h0[1], h0[2], h0[3]};
      u0.v[1] = (v4h){h0[4], h0[5], h0[6], h0[7]};
      u1.v[0] = (v4h){h1[0], h1[1], h1[2], h1[3]};
      u1.v[1] = (v4h){h1[4], h1[5], h1[6], h1[7]};
      *(float4*)&Kl[tid * 8]         = u0.f;
      *(float4*)&Kl[(tid + 256) * 8] = u1.f;

      // VT with within-16 slot perm (swap bits 2<->3 of key index)
      const int j0 = tid, j1 = tid + 256;
      const int col0 = (j0 & ~15) | (j0 & 3) | ((j0 & 4) << 1) | ((j0 & 8) >> 1);
      const int col1 = (j1 & ~15) | (j1 & 3) | ((j1 & 4) << 1) | ((j1 & 8) >> 1);
#pragma unroll
      for (int d = 0; d < 8; ++d) {
        VT[d][col0] = h0[d];
        VT[d][col1] = h1[d];
      }
    }
    __syncthreads();

    // prefetch the second chunk's x rows (consumed after this compute phase)
    if (cc == 0) {
      const float* xp = xb + (size_t)((kh * 2 + 1) * CHUNK + tid) * EMB;
      pa0 = *(const float4*)(xp);
      pa1 = *(const float4*)(xp + 4);
      pb0 = *(const float4*)(xp + 256 * EMB);
      pb1 = *(const float4*)(xp + 256 * EMB + 4);
    }

    // ---- compute: 16 32-key blocks, software-pipelined ----
    v8h kf_next = *(const v8h*)&Kl[ln * 8];   // kb = 0
#pragma unroll 2
    for (int kb = 0; kb < CHUNK / 32; ++kb) {
      const v8h kf = kf_next;
      // issue the S-mfma first, then prefetch next kf + this kb's vt while
      // the mfma and exps run
      const v16f s = __builtin_amdgcn_mfma_f32_32x32x16_f16(kf, qf, zf, 0, 0, 0);
      if (kb + 1 < CHUNK / 32)
        kf_next = *(const v8h*)&Kl[((kb + 1) * 32 + ln) * 8];
      const v8h vt0 = *(const v8h*)&VT[mrow][kb * 32 + hf * 8];
      const v8h vt1 = *(const v8h*)&VT[mrow][kb * 32 + 16 + hf * 8];
      union { v2fp p[4]; v8h v; } p0, p1;
#pragma unroll
      for (int i = 0; i < 4; ++i) {
        p0.p[i] = __builtin_amdgcn_cvt_pkrtz(
            __builtin_amdgcn_exp2f(s[2 * i]),
            __builtin_amdgcn_exp2f(s[2 * i + 1]));
        p1.p[i] = __builtin_amdgcn_cvt_pkrtz(
            __builtin_amdgcn_exp2f(s[8 + 2 * i]),
            __builtin_amdgcn_exp2f(s[8 + 2 * i + 1]));
      }
      acc = __builtin_amdgcn_mfma_f32_32x32x16_f16(vt0, p0.v, acc, 0, 0, 0);
      acc = __builtin_amdgcn_mfma_f32_32x32x16_f16(vt1, p1.v, acc, 0, 0, 0);
    }
  }

  // ---- epilogue: write unnormalized partial (no division, no shfl) ----
  // acc C-layout: col=q=L&31, row=(reg&3)+8(reg>>2)+4*hf.
  // half0 regs 0-3 = dims 0-3, reg4 = row 8 = den; half1 regs 0-3 = dims 4-7.
  {
    const int qrow = qb + ln;
    const size_t pbase = ((((size_t)kh * BATCH + b) * NH + h) * SEQ + qrow);
    const float4 o = {acc[0], acc[1], acc[2], acc[3]};
    *(float4*)&PO[pbase * 8 + (size_t)hf * 4] = o;
    if (hf == 0) DEN[pbase] = acc[4];
  }
}

// ---------------------------------------------------------------------------
// MFMA projection. Stages Ah by COMBINING the two key-half partials
// (o = (p0+p1)/(den0+den1)) straight into LDS f16, then out = Ah · W^T.
// W row-major IS the B-fragment source. Block: 64 rows x 64 cols
// (grid 128x2), LDS 35 KB, 4 blocks/CU.
// ---------------------------------------------------------------------------
__launch_bounds__(256, 4)
__global__ void proj_kernel(const float* __restrict__ PO,
                            const float* __restrict__ DEN,
                            const float* __restrict__ W,
                            float* __restrict__ out) {
  __shared__ __align__(16) _Float16 Ahs[64][136];
  __shared__ __align__(16) _Float16 Whs[64][136];

  const int tid  = threadIdx.x;
  const int L    = tid & 63;
  const int wv   = tid >> 6;
  const int quad = L >> 4;
  const int ln   = L & 15;
  const int rowbase = blockIdx.x * 64;
  const int colbase = blockIdx.y * 64;

  // combine partials -> Ah tile. idx -> (h, r): consecutive lanes take
  // consecutive rows for a fixed head => PO reads are 2 KB contiguous/wave.
#pragma unroll
  for (int it = 0; it < 4; ++it) {
    const int idx = it * 256 + tid;     // 0..1023 = 16 heads x 64 rows
    const int hh = idx >> 6;
    const int r  = idx & 63;
    const size_t srow = (size_t)rowbase + r;
    const int bb = (int)(srow >> 11);
    const int sl = (int)(srow & 2047);
    const size_t p0 = ((((size_t)0 * BATCH + bb) * NH + hh) * SEQ + sl);
    const size_t p1 = ((((size_t)1 * BATCH + bb) * NH + hh) * SEQ + sl);
    const float4 a0 = *(const float4*)&PO[p0 * 8];
    const float4 b0 = *(const float4*)&PO[p0 * 8 + 4];
    const float4 a1 = *(const float4*)&PO[p1 * 8];
    const float4 b1 = *(const float4*)&PO[p1 * 8 + 4];
    const float inv = 1.0f / (DEN[p0] + DEN[p1]);
    const v4h lo = {(_Float16)((a0.x + a1.x) * inv), (_Float16)((a0.y + a1.y) * inv),
                    (_Float16)((a0.z + a1.z) * inv), (_Float16)((a0.w + a1.w) * inv)};
    const v4h hi = {(_Float16)((b0.x + b1.x) * inv), (_Float16)((b0.y + b1.y) * inv),
                    (_Float16)((b0.z + b1.z) * inv), (_Float16)((b0.w + b1.w) * inv)};
    *(v4h*)&Ahs[r][hh * 8]     = lo;
    *(v4h*)&Ahs[r][hh * 8 + 4] = hi;
  }
#pragma unroll
  for (int it = 0; it < 8; ++it) {
    const int idx = it * 256 + tid;
    const int n  = idx >> 5;
    const int c4 = idx & 31;
    const float4 w = *(const float4*)(W + (size_t)(colbase + n) * EMB + c4 * 4);
    v4h wh = {(_Float16)w.x, (_Float16)w.y, (_Float16)w.z, (_Float16)w.w};
    *(v4h*)&Whs[n][c4 * 4] = wh;
  }
  __syncthreads();

  v4f acc[4];
#pragma unroll
  for (int nt = 0; nt < 4; ++nt) acc[nt] = (v4f){0.f, 0.f, 0.f, 0.f};

#pragma unroll
  for (int k8 = 0; k8 < 8; ++k8) {
    const v4h af = *(const v4h*)&Ahs[wv * 16 + ln][k8 * 16 + quad * 4];
#pragma unroll
    for (int nt = 0; nt < 4; ++nt) {
      const v4h bf = *(const v4h*)&Whs[nt * 16 + ln][k8 * 16 + quad * 4];
      acc[nt] = __builtin_amdgcn_mfma_f32_16x16x16f16(af, bf, acc[nt], 0, 0, 0);
    }
  }

#pragma unroll
  for (int nt = 0; nt < 4; ++nt) {
    const int col = colbase + nt * 16 + ln;
#pragma unroll
    for (int r = 0; r < 4; ++r) {
      out[(size_t)(rowbase + wv * 16 + quad * 4 + r) * EMB + col] = acc[nt][r];
    }
  }
}

// ---------------------------------------------------------------------------
extern "C" void kernel_launch(void* const* d_in, const int* in_sizes, int n_in,
                              void* d_out, int out_size, void* d_ws, size_t ws_size,
                              hipStream_t stream) {
  const float* x     = (const float*)d_in[0];  // [4,2048,128]
  const float* theta = (const float*)d_in[1];  // [8]
  const float* w_out = (const float*)d_in[2];  // [128,128]
  float* out = (float*)d_out;                  // [4,2048,128]

  // workspace: PO [2][B][NH][S][8] f32 (8 MB) + DEN [2][B][NH][S] f32 (1 MB)
  float* PO  = (float*)d_ws;
  float* DEN = PO + (size_t)2 * BATCH * NH * SEQ * 8;

  // fused features + attention, key-split 2-way:
  // 64 bh x 16 q-chunks x 2 key-halves = 2048 blocks, 4 waves, 8 blocks/CU
  attn_kernel<<<dim3(2048), dim3(256), 0, stream>>>(x, theta, PO, DEN);

  // projection + partial combine: 128 row-tiles x 2 col-tiles
  proj_kernel<<<dim3((BATCH * SEQ) / 64, 2), dim3(256), 0, stream>>>(PO, DEN, w_out, out);
}